// Round 12
// baseline (417.458 us; speedup 1.0000x reference)
//
#include <hip/hip_runtime.h>
#include <stdint.h>

#define NA 9
#define HH 50
#define WW 50
#define NPROP (HH*WW*NA)      // 22500
#define PRE_NMS 4000
#define POST_NMS 300
#define NWORDS 63             // windows (64 candidates each)
#define MROWS 4032            // 63*64 padded rows per image
#define SELN 8192             // compaction capacity
#define NMS_T 0.7f
#define FSTRIDE 16.0f
#define NBLK 256
#define NTHR 256

typedef unsigned long long ull;

__device__ __forceinline__ uint32_t f32_ord(float s) {
    uint32_t u = __float_as_uint(s);
    return (u & 0x80000000u) ? ~u : (u | 0x80000000u);
}

// Device-scope grid barrier. Counters zeroed by the memset node each launch.
// All 256 blocks are co-resident (1 block/CU) => no deadlock.
__device__ __forceinline__ void gbar(int* bar, int k) {
    __threadfence();
    __syncthreads();
    if (threadIdx.x == 0) {
        atomicAdd(&bar[k], 1);
        while (atomicAdd(&bar[k], 0) < NBLK) __builtin_amdgcn_s_sleep(8);
    }
    __syncthreads();
    __threadfence();
}

__global__ __launch_bounds__(NTHR) void proposal_all(
        const float* __restrict__ scores,
        const float* __restrict__ deltas,
        const float* __restrict__ im_info,
        const float* __restrict__ anchors,
        uint32_t* __restrict__ hist,     // B*4096, zeroed
        int* __restrict__ cnt,           // B, zeroed
        int* __restrict__ bar,           // 8, zeroed
        float4* __restrict__ boxes4,
        ull* __restrict__ keys,
        ull* __restrict__ ckeys,
        float4* __restrict__ gboxes,
        ull* __restrict__ mask,
        float* __restrict__ out, int B) {
    __shared__ __align__(16) char pool[65536];
    __shared__ int sA[NTHR], sB[NTHR];
    __shared__ int sThr[8];
    __shared__ int keepIdx[POST_NMS];
    __shared__ int sKept, sDone;

    const int bid = blockIdx.x, tid = threadIdx.x;
    const int lane = tid & 63, wid = tid >> 6;

    // ===================== P1: decode + keys + 12-bit histogram ===========
    for (int i0 = bid * NTHR; i0 < B * NPROP; i0 += NBLK * NTHR) {
        int t = i0 + tid;
        if (t < B * NPROP) {
            int img = t / NPROP;
            int i   = t - img * NPROP;
            int a   = i % NA;
            int pos = i / NA;
            int w   = pos % WW;
            int h   = pos / WW;

            float score = scores[((size_t)img*2*NA + NA + a)*(HH*WW) + pos];
            uint32_t so = f32_ord(score);
            keys[t] = ((ull)so << 32) | (ull)(0xFFFFFFFFu - (uint32_t)i);
            atomicAdd(&hist[((uint32_t)img << 12) | (so >> 20)], 1u);

            float ax1 = anchors[a*4+0], ay1 = anchors[a*4+1];
            float ax2 = anchors[a*4+2], ay2 = anchors[a*4+3];
            float sx = (float)w * FSTRIDE, sy = (float)h * FSTRIDE;
            float x1 = ax1 + sx, y1 = ay1 + sy, x2 = ax2 + sx, y2 = ay2 + sy;
            float bw = x2 - x1 + 1.0f;
            float bh = y2 - y1 + 1.0f;
            float cx = x1 + 0.5f * bw;
            float cy = y1 + 0.5f * bh;

            const float* dp = deltas + (size_t)img*4*NA*(HH*WW);
            float dx = dp[(4*a+0)*(HH*WW)+pos];
            float dy = dp[(4*a+1)*(HH*WW)+pos];
            float dw = dp[(4*a+2)*(HH*WW)+pos];
            float dh = dp[(4*a+3)*(HH*WW)+pos];

            float pcx = dx * bw + cx;
            float pcy = dy * bh + cy;
            float pw  = expf(dw) * bw;
            float ph  = expf(dh) * bh;

            float wmax = im_info[img*3+1] - 1.0f;
            float hmax = im_info[img*3+0] - 1.0f;
            float px1 = fminf(fmaxf(pcx - 0.5f*pw, 0.0f), wmax);
            float py1 = fminf(fmaxf(pcy - 0.5f*ph, 0.0f), hmax);
            float px2 = fminf(fmaxf(pcx + 0.5f*pw, 0.0f), wmax);
            float py2 = fminf(fmaxf(pcy + 0.5f*ph, 0.0f), hmax);

            boxes4[t] = make_float4(px1, py1, px2, py2);
        }
    }
    gbar(bar, 0);

    // ===================== P2: threshold (redundant per block) + compact ===
    for (int img = 0; img < B; ++img) {
        const uint32_t* h = hist + ((uint32_t)img << 12);
        {   // coarse sums: 16 buckets per thread
            const uint4* h4 = (const uint4*)h;
            uint32_t s = 0;
            #pragma unroll
            for (int u = 0; u < 4; ++u) {
                uint4 v = h4[(tid << 2) | u];
                s += v.x + v.y + v.z + v.w;
            }
            sA[tid] = (int)s;
        }
        __syncthreads();
        int* curp = sA; int* nxtp = sB;
        for (int d = 1; d < NTHR; d <<= 1) {
            int v = curp[tid] + ((tid + d < NTHR) ? curp[tid + d] : 0);
            nxtp[tid] = v;
            __syncthreads();
            int* tmp = curp; curp = nxtp; nxtp = tmp;
        }
        {
            int c0 = curp[tid];
            int c1 = (tid < NTHR-1) ? curp[tid + 1] : 0;
            if (c0 >= PRE_NMS && c1 < PRE_NMS) {
                int cum = c1, t = tid << 4;
                for (int w = 15; w >= 0; --w) {
                    int nc = cum + (int)h[(tid << 4) + w];
                    if (nc >= PRE_NMS) { t = (tid << 4) + w; break; }
                    cum = nc;
                }
                sThr[img] = t;
            }
        }
        __syncthreads();
    }
    // compact with wave-aggregated atomics
    for (int img = 0; img < B; ++img) {
        int th = sThr[img];
        const ull* kb = keys + (size_t)img * NPROP;
        ull* ck = ckeys + (size_t)img * SELN;
        for (int i0 = bid * NTHR; i0 < NPROP; i0 += NBLK * NTHR) {
            int i = i0 + tid;
            ull key = 0; bool q = false;
            if (i < NPROP) { key = kb[i]; q = ((int)(key >> 52) >= th); }
            ull ball = __ballot(q);
            if (ball) {
                int leader = __builtin_ctzll(ball);
                int nb = __popcll(ball);
                int basep = 0;
                if (lane == leader) basep = atomicAdd(&cnt[img], nb);
                basep = __shfl(basep, leader);
                if (q) {
                    int p = basep + __popcll(ball & ((1ull << lane) - 1ull));
                    if (p < SELN) ck[p] = key;
                }
            }
        }
    }
    gbar(bar, 1);

    // ===================== P3: rank-by-count scatter ======================
    if (bid < B * 32) {
        int img = bid >> 5, tile = bid & 31;
        int M = cnt[img]; if (M > SELN) M = SELN;
        if (tile * NTHR < M) {
            ull* lk = (ull*)pool;
            int Ms = (M + NTHR - 1) & ~(NTHR - 1);
            const ull* kb = ckeys + (size_t)img * SELN;
            for (int e = tid; e < Ms; e += NTHR) lk[e] = (e < M) ? kb[e] : 0ull;
            __syncthreads();
            int row = tile * NTHR + tid;
            if (row < M) {
                ull my = lk[row];
                int rank = 0;
                #pragma unroll 8
                for (int e = 0; e < Ms; ++e) rank += (lk[e] > my) ? 1 : 0;
                if (rank < PRE_NMS) {
                    uint32_t idx = 0xFFFFFFFFu - (uint32_t)(my & 0xFFFFFFFFull);
                    gboxes[(size_t)img*PRE_NMS + rank] = boxes4[(size_t)img*NPROP + idx];
                }
            }
        }
    }
    gbar(bar, 2);

    // ===================== P4: suppression bit-matrix =====================
    // 2016 upper-tri 64x64 tile-pairs per image over 1024 wave-slots.
    {
        float* st = (float*)(pool + wid * 1536);
        float* scx1 = st;        float* scy1 = st + 64;
        float* scx2 = st + 128;  float* scy2 = st + 192;
        float* scar = st + 256;
        const int npairs = NWORDS * (NWORDS + 1) / 2;   // 2016
        const int total = B * npairs;
        const int slots = NBLK * 4;
        const int trips = (total + slots - 1) / slots;
        for (int it = 0; it < trips; ++it) {
            int pid = it * slots + bid * 4 + wid;
            bool act = pid < total;
            int b = 0, rb = 0, cb = 0;
            if (act) {
                b = pid / npairs;
                int rem = pid - b * npairs;
                while (rem >= NWORDS - rb) { rem -= NWORDS - rb; ++rb; }
                cb = rb + rem;
            }
            if (act) {
                int j0 = cb * 64 + lane;
                float4 cbx = (j0 < PRE_NMS) ? gboxes[(size_t)b*PRE_NMS + j0]
                                            : make_float4(0.f, 0.f, 0.f, 0.f);
                scx1[lane] = cbx.x; scy1[lane] = cbx.y;
                scx2[lane] = cbx.z; scy2[lane] = cbx.w;
                scar[lane] = (cbx.z - cbx.x + 1.0f) * (cbx.w - cbx.y + 1.0f);
            }
            __syncthreads();
            if (act) {
                int i = rb * 64 + lane;
                if (i < PRE_NMS) {
                    float4 rbx = gboxes[(size_t)b*PRE_NMS + i];
                    float ix1 = rbx.x, iy1 = rbx.y, ix2 = rbx.z, iy2 = rbx.w;
                    float iarea = (ix2 - ix1 + 1.0f) * (iy2 - iy1 + 1.0f);
                    const bool diag = (rb == cb);
                    ull bits = 0;
                    #pragma unroll 16
                    for (int k = 0; k < 64; ++k) {
                        float xx1 = fmaxf(ix1, scx1[k]);
                        float yy1 = fmaxf(iy1, scy1[k]);
                        float xx2 = fminf(ix2, scx2[k]);
                        float yy2 = fminf(iy2, scy2[k]);
                        float ww = fmaxf(xx2 - xx1 + 1.0f, 0.0f);
                        float hh = fmaxf(yy2 - yy1 + 1.0f, 0.0f);
                        float inter = ww * hh;
                        float iou = inter / (iarea + scar[k] - inter);
                        // diag slot is TRANSPOSED: bit k = row k suppresses col lane
                        bool cond = diag ? (lane > k) : ((cb * 64 + k) < PRE_NMS);
                        if (cond & (iou > NMS_T)) bits |= (1ull << k);
                    }
                    mask[(((size_t)b*MROWS + i) << 6) + cb] = bits;
                }
            }
            __syncthreads();
        }
    }
    gbar(bar, 3);

    // ===================== P5: greedy scan (R9 v4, 4-wave staging) ========
    if (bid < B) {
        int b = bid;
        ull* buf0 = (ull*)pool;              // [64][64]
        ull* buf1 = (ull*)pool + 4096;       // [64][64]
        const ull* mbase = mask + ((size_t)b * MROWS << 6);

        {   // stage window 0 with all 256 threads
            const ulonglong2* src = (const ulonglong2*)mbase;
            ulonglong2* dst = (ulonglong2*)buf0;
            #pragma unroll
            for (int k = 0; k < 8; ++k) dst[tid + k*NTHR] = src[tid + k*NTHR];
        }
        if (tid == 0) { sDone = 0; sKept = 0; }
        __syncthreads();

        ull supp = 0;
        if (lane == NWORDS-1) supp = 0xFFFFFFFF00000000ull;  // cands >= 4000
        if (lane >= NWORDS)   supp = ~0ull;
        int kept = 0;
        int cur = 0;

        for (int wi = 0; wi < NWORDS; ++wi) {
            ulonglong2 pf[8];
            bool havepf = (wi + 1 < NWORDS);
            if (havepf) {
                const ulonglong2* src =
                    (const ulonglong2*)(mbase + ((size_t)(wi + 1) << 12));
                #pragma unroll
                for (int k = 0; k < 8; ++k) pf[k] = src[tid + k*NTHR];
            }
            if (wid == 0) {
                ull* bc = cur ? buf1 : buf0;
                ull tw = bc[lane * 64 + wi];          // transposed diag word
                ull avail = ~__shfl(supp, wi);
                ull keptmask = 0;
                bool done = false;
                while (avail) {
                    int c = __builtin_ctzll(avail);
                    if (lane == 0) keepIdx[kept] = (wi << 6) + c;
                    ++kept;
                    keptmask |= (1ull << c);
                    if (kept >= POST_NMS) { done = true; break; }
                    ull roww = __ballot((int)((tw >> c) & 1ull));
                    avail &= ~roww;
                    avail &= avail - 1;
                }
                if (!done) {
                    ull km = keptmask;
                    while (km) {
                        int c = __builtin_ctzll(km); km &= km - 1;
                        ull r = (lane > wi && lane < NWORDS) ? bc[c * 64 + lane] : 0ull;
                        supp |= r;
                    }
                }
                if (lane == 0) { sKept = kept; sDone = done ? 1 : 0; }
            }
            __syncthreads();
            if (sDone) break;
            if (havepf) {
                ulonglong2* dst = (ulonglong2*)(cur ? buf0 : buf1);
                #pragma unroll
                for (int k = 0; k < 8; ++k) dst[tid + k*NTHR] = pf[k];
            }
            __syncthreads();
            cur ^= 1;
        }
        __syncthreads();
        int kfin = sKept;
        for (int r = tid; r < POST_NMS; r += NTHR) {
            float4 bx = (r < kfin) ? gboxes[(size_t)b*PRE_NMS + keepIdx[r]]
                                   : make_float4(0.f, 0.f, 0.f, 0.f);
            float* o = out + (size_t)(b*POST_NMS + r)*5;
            o[0] = (float)b; o[1] = bx.x; o[2] = bx.y; o[3] = bx.z; o[4] = bx.w;
        }
    }
}

// ---------------------------------------------------------------------------
extern "C" void kernel_launch(void* const* d_in, const int* in_sizes, int n_in,
                              void* d_out, int out_size, void* d_ws, size_t ws_size,
                              hipStream_t stream) {
    (void)n_in; (void)out_size; (void)ws_size;
    const float* scores  = (const float*)d_in[0];
    const float* deltas  = (const float*)d_in[1];
    const float* im_info = (const float*)d_in[2];
    const float* anchors = (const float*)d_in[3];
    float* out = (float*)d_out;

    const int B = in_sizes[0] / (2*NA*HH*WW);   // = 2

    // ws layout: [hist B*4096 u32 | cnt 8 int | bar 8 int] (zeroed) | boxes4 |
    //            keys | ckeys | gboxes | mask
    size_t histB = (size_t)B * 4096 * sizeof(uint32_t);
    uint32_t* hist = (uint32_t*)d_ws;
    int* cnt = (int*)((char*)d_ws + histB);
    int* bar = cnt + 8;
    float4* boxes4 = (float4*)((char*)d_ws + histB + 64);
    ull* keys  = (ull*)(boxes4 + (size_t)B*NPROP);
    ull* ckeys = keys + (size_t)B*NPROP;
    float4* gboxes = (float4*)(ckeys + (size_t)B*SELN);
    ull* mask = (ull*)(gboxes + (size_t)B*PRE_NMS);

    hipMemsetAsync(d_ws, 0, histB + 64, stream);
    proposal_all<<<NBLK, NTHR, 0, stream>>>(scores, deltas, im_info, anchors,
                                            hist, cnt, bar,
                                            boxes4, keys, ckeys, gboxes, mask,
                                            out, B);
}

// Round 13
// 403.519 us; speedup vs baseline: 1.0345x; 1.0345x over previous
//
#include <hip/hip_runtime.h>
#include <stdint.h>

#define NA 9
#define HH 50
#define WW 50
#define NPROP (HH*WW*NA)      // 22500
#define PRE_NMS 4000
#define POST_NMS 300
#define NWORDS 63             // windows (64 candidates each)
#define MROWS 4032            // 63*64 padded rows per image
#define SELN 8192             // compaction capacity
#define NMS_T 0.7f
#define FSTRIDE 16.0f
#define NBLK 256
#define NTHR 256

typedef unsigned long long ull;

__device__ __forceinline__ uint32_t f32_ord(float s) {
    uint32_t u = __float_as_uint(s);
    return (u & 0x80000000u) ? ~u : (u | 0x80000000u);
}

// RMW-free device-scope grid barrier (epoch flags, cooperative load-poll).
// Arrive: one plain store per block (distinct addresses -> parallel).
// Wait: each thread polls one flag; __syncthreads_and reduces. Skew-safe via
// >= epoch (a fast block may already have posted epoch+1). Flags zeroed by
// the memset node each launch. All 256 blocks co-resident => no deadlock.
__device__ __forceinline__ void gbar(uint32_t* flags, uint32_t epoch) {
    __threadfence();                      // release prior writes
    __syncthreads();
    if (threadIdx.x == 0)
        __hip_atomic_store(&flags[blockIdx.x], epoch,
                           __ATOMIC_RELEASE, __HIP_MEMORY_SCOPE_AGENT);
    int ok;
    do {
        uint32_t v = epoch;
        if (threadIdx.x < NBLK)
            v = __hip_atomic_load(&flags[threadIdx.x],
                                  __ATOMIC_RELAXED, __HIP_MEMORY_SCOPE_AGENT);
        ok = __syncthreads_and((int)(v >= epoch));
        if (!ok) __builtin_amdgcn_s_sleep(16);
    } while (!ok);
    __threadfence();                      // acquire other blocks' writes
}

__global__ __launch_bounds__(NTHR) void proposal_all(
        const float* __restrict__ scores,
        const float* __restrict__ deltas,
        const float* __restrict__ im_info,
        const float* __restrict__ anchors,
        uint32_t* __restrict__ hist,     // B*4096, zeroed
        int* __restrict__ cnt,           // B, zeroed
        uint32_t* __restrict__ flags,    // NBLK, zeroed
        float4* __restrict__ boxes4,
        ull* __restrict__ keys,
        ull* __restrict__ ckeys,
        float4* __restrict__ gboxes,
        ull* __restrict__ mask,
        float* __restrict__ out, int B) {
    __shared__ __align__(16) char pool[65536];
    __shared__ int sA[NTHR], sB[NTHR];
    __shared__ int sThr[8];
    __shared__ int keepIdx[POST_NMS];
    __shared__ int sKept, sDone;

    const int bid = blockIdx.x, tid = threadIdx.x;
    const int lane = tid & 63, wid = tid >> 6;

    // ===================== P1: decode + keys + 12-bit histogram ===========
    for (int i0 = bid * NTHR; i0 < B * NPROP; i0 += NBLK * NTHR) {
        int t = i0 + tid;
        if (t < B * NPROP) {
            int img = t / NPROP;
            int i   = t - img * NPROP;
            int a   = i % NA;
            int pos = i / NA;
            int w   = pos % WW;
            int h   = pos / WW;

            float score = scores[((size_t)img*2*NA + NA + a)*(HH*WW) + pos];
            uint32_t so = f32_ord(score);
            keys[t] = ((ull)so << 32) | (ull)(0xFFFFFFFFu - (uint32_t)i);
            atomicAdd(&hist[((uint32_t)img << 12) | (so >> 20)], 1u);

            float ax1 = anchors[a*4+0], ay1 = anchors[a*4+1];
            float ax2 = anchors[a*4+2], ay2 = anchors[a*4+3];
            float sx = (float)w * FSTRIDE, sy = (float)h * FSTRIDE;
            float x1 = ax1 + sx, y1 = ay1 + sy, x2 = ax2 + sx, y2 = ay2 + sy;
            float bw = x2 - x1 + 1.0f;
            float bh = y2 - y1 + 1.0f;
            float cx = x1 + 0.5f * bw;
            float cy = y1 + 0.5f * bh;

            const float* dp = deltas + (size_t)img*4*NA*(HH*WW);
            float dx = dp[(4*a+0)*(HH*WW)+pos];
            float dy = dp[(4*a+1)*(HH*WW)+pos];
            float dw = dp[(4*a+2)*(HH*WW)+pos];
            float dh = dp[(4*a+3)*(HH*WW)+pos];

            float pcx = dx * bw + cx;
            float pcy = dy * bh + cy;
            float pw  = expf(dw) * bw;
            float ph  = expf(dh) * bh;

            float wmax = im_info[img*3+1] - 1.0f;
            float hmax = im_info[img*3+0] - 1.0f;
            float px1 = fminf(fmaxf(pcx - 0.5f*pw, 0.0f), wmax);
            float py1 = fminf(fmaxf(pcy - 0.5f*ph, 0.0f), hmax);
            float px2 = fminf(fmaxf(pcx + 0.5f*pw, 0.0f), wmax);
            float py2 = fminf(fmaxf(pcy + 0.5f*ph, 0.0f), hmax);

            boxes4[t] = make_float4(px1, py1, px2, py2);
        }
    }
    gbar(flags, 1u);

    // ===================== P2: threshold (redundant per block) + compact ===
    for (int img = 0; img < B; ++img) {
        const uint32_t* h = hist + ((uint32_t)img << 12);
        {   // coarse sums: 16 buckets per thread
            const uint4* h4 = (const uint4*)h;
            uint32_t s = 0;
            #pragma unroll
            for (int u = 0; u < 4; ++u) {
                uint4 v = h4[(tid << 2) | u];
                s += v.x + v.y + v.z + v.w;
            }
            sA[tid] = (int)s;
        }
        __syncthreads();
        int* curp = sA; int* nxtp = sB;
        for (int d = 1; d < NTHR; d <<= 1) {
            int v = curp[tid] + ((tid + d < NTHR) ? curp[tid + d] : 0);
            nxtp[tid] = v;
            __syncthreads();
            int* tmp = curp; curp = nxtp; nxtp = tmp;
        }
        {
            int c0 = curp[tid];
            int c1 = (tid < NTHR-1) ? curp[tid + 1] : 0;
            if (c0 >= PRE_NMS && c1 < PRE_NMS) {
                int cum = c1, t = tid << 4;
                for (int w = 15; w >= 0; --w) {
                    int nc = cum + (int)h[(tid << 4) + w];
                    if (nc >= PRE_NMS) { t = (tid << 4) + w; break; }
                    cum = nc;
                }
                sThr[img] = t;
            }
        }
        __syncthreads();
    }
    // compact with wave-aggregated atomics
    for (int img = 0; img < B; ++img) {
        int th = sThr[img];
        const ull* kb = keys + (size_t)img * NPROP;
        ull* ck = ckeys + (size_t)img * SELN;
        for (int i0 = bid * NTHR; i0 < NPROP; i0 += NBLK * NTHR) {
            int i = i0 + tid;
            ull key = 0; bool q = false;
            if (i < NPROP) { key = kb[i]; q = ((int)(key >> 52) >= th); }
            ull ball = __ballot(q);
            if (ball) {
                int leader = __builtin_ctzll(ball);
                int nb = __popcll(ball);
                int basep = 0;
                if (lane == leader) basep = atomicAdd(&cnt[img], nb);
                basep = __shfl(basep, leader);
                if (q) {
                    int p = basep + __popcll(ball & ((1ull << lane) - 1ull));
                    if (p < SELN) ck[p] = key;
                }
            }
        }
    }
    gbar(flags, 2u);

    // ===================== P3: rank-by-count scatter ======================
    if (bid < B * 32) {
        int img = bid >> 5, tile = bid & 31;
        int M = cnt[img]; if (M > SELN) M = SELN;
        if (tile * NTHR < M) {
            ull* lk = (ull*)pool;
            int Ms = (M + NTHR - 1) & ~(NTHR - 1);
            const ull* kb = ckeys + (size_t)img * SELN;
            for (int e = tid; e < Ms; e += NTHR) lk[e] = (e < M) ? kb[e] : 0ull;
            __syncthreads();
            int row = tile * NTHR + tid;
            if (row < M) {
                ull my = lk[row];
                int rank = 0;
                #pragma unroll 8
                for (int e = 0; e < Ms; ++e) rank += (lk[e] > my) ? 1 : 0;
                if (rank < PRE_NMS) {
                    uint32_t idx = 0xFFFFFFFFu - (uint32_t)(my & 0xFFFFFFFFull);
                    gboxes[(size_t)img*PRE_NMS + rank] = boxes4[(size_t)img*NPROP + idx];
                }
            }
        }
    }
    gbar(flags, 3u);

    // ===================== P4: suppression bit-matrix =====================
    // 2016 upper-tri 64x64 tile-pairs per image over 1024 wave-slots.
    {
        float* st = (float*)(pool + wid * 1536);
        float* scx1 = st;        float* scy1 = st + 64;
        float* scx2 = st + 128;  float* scy2 = st + 192;
        float* scar = st + 256;
        const int npairs = NWORDS * (NWORDS + 1) / 2;   // 2016
        const int total = B * npairs;
        const int slots = NBLK * 4;
        const int trips = (total + slots - 1) / slots;
        for (int it = 0; it < trips; ++it) {
            int pid = it * slots + bid * 4 + wid;
            bool act = pid < total;
            int b = 0, rb = 0, cb = 0;
            if (act) {
                b = pid / npairs;
                int rem = pid - b * npairs;
                while (rem >= NWORDS - rb) { rem -= NWORDS - rb; ++rb; }
                cb = rb + rem;
            }
            if (act) {
                int j0 = cb * 64 + lane;
                float4 cbx = (j0 < PRE_NMS) ? gboxes[(size_t)b*PRE_NMS + j0]
                                            : make_float4(0.f, 0.f, 0.f, 0.f);
                scx1[lane] = cbx.x; scy1[lane] = cbx.y;
                scx2[lane] = cbx.z; scy2[lane] = cbx.w;
                scar[lane] = (cbx.z - cbx.x + 1.0f) * (cbx.w - cbx.y + 1.0f);
            }
            __syncthreads();
            if (act) {
                int i = rb * 64 + lane;
                if (i < PRE_NMS) {
                    float4 rbx = gboxes[(size_t)b*PRE_NMS + i];
                    float ix1 = rbx.x, iy1 = rbx.y, ix2 = rbx.z, iy2 = rbx.w;
                    float iarea = (ix2 - ix1 + 1.0f) * (iy2 - iy1 + 1.0f);
                    const bool diag = (rb == cb);
                    ull bits = 0;
                    #pragma unroll 16
                    for (int k = 0; k < 64; ++k) {
                        float xx1 = fmaxf(ix1, scx1[k]);
                        float yy1 = fmaxf(iy1, scy1[k]);
                        float xx2 = fminf(ix2, scx2[k]);
                        float yy2 = fminf(iy2, scy2[k]);
                        float ww = fmaxf(xx2 - xx1 + 1.0f, 0.0f);
                        float hh = fmaxf(yy2 - yy1 + 1.0f, 0.0f);
                        float inter = ww * hh;
                        float iou = inter / (iarea + scar[k] - inter);
                        // diag slot is TRANSPOSED: bit k = row k suppresses col lane
                        bool cond = diag ? (lane > k) : ((cb * 64 + k) < PRE_NMS);
                        if (cond & (iou > NMS_T)) bits |= (1ull << k);
                    }
                    mask[(((size_t)b*MROWS + i) << 6) + cb] = bits;
                }
            }
            __syncthreads();
        }
    }
    gbar(flags, 4u);

    // ===================== P5: greedy scan (R9 v4, 4-wave staging) ========
    if (bid < B) {
        int b = bid;
        ull* buf0 = (ull*)pool;              // [64][64]
        ull* buf1 = (ull*)pool + 4096;       // [64][64]
        const ull* mbase = mask + ((size_t)b * MROWS << 6);

        {   // stage window 0 with all 256 threads
            const ulonglong2* src = (const ulonglong2*)mbase;
            ulonglong2* dst = (ulonglong2*)buf0;
            #pragma unroll
            for (int k = 0; k < 8; ++k) dst[tid + k*NTHR] = src[tid + k*NTHR];
        }
        if (tid == 0) { sDone = 0; sKept = 0; }
        __syncthreads();

        ull supp = 0;
        if (lane == NWORDS-1) supp = 0xFFFFFFFF00000000ull;  // cands >= 4000
        if (lane >= NWORDS)   supp = ~0ull;
        int kept = 0;
        int cur = 0;

        for (int wi = 0; wi < NWORDS; ++wi) {
            ulonglong2 pf[8];
            bool havepf = (wi + 1 < NWORDS);
            if (havepf) {
                const ulonglong2* src =
                    (const ulonglong2*)(mbase + ((size_t)(wi + 1) << 12));
                #pragma unroll
                for (int k = 0; k < 8; ++k) pf[k] = src[tid + k*NTHR];
            }
            if (wid == 0) {
                ull* bc = cur ? buf1 : buf0;
                ull tw = bc[lane * 64 + wi];          // transposed diag word
                ull avail = ~__shfl(supp, wi);
                ull keptmask = 0;
                bool done = false;
                while (avail) {
                    int c = __builtin_ctzll(avail);
                    if (lane == 0) keepIdx[kept] = (wi << 6) + c;
                    ++kept;
                    keptmask |= (1ull << c);
                    if (kept >= POST_NMS) { done = true; break; }
                    ull roww = __ballot((int)((tw >> c) & 1ull));
                    avail &= ~roww;
                    avail &= avail - 1;
                }
                if (!done) {
                    ull km = keptmask;
                    while (km) {
                        int c = __builtin_ctzll(km); km &= km - 1;
                        ull r = (lane > wi && lane < NWORDS) ? bc[c * 64 + lane] : 0ull;
                        supp |= r;
                    }
                }
                if (lane == 0) { sKept = kept; sDone = done ? 1 : 0; }
            }
            __syncthreads();
            if (sDone) break;
            if (havepf) {
                ulonglong2* dst = (ulonglong2*)(cur ? buf0 : buf1);
                #pragma unroll
                for (int k = 0; k < 8; ++k) dst[tid + k*NTHR] = pf[k];
            }
            __syncthreads();
            cur ^= 1;
        }
        __syncthreads();
        int kfin = sKept;
        for (int r = tid; r < POST_NMS; r += NTHR) {
            float4 bx = (r < kfin) ? gboxes[(size_t)b*PRE_NMS + keepIdx[r]]
                                   : make_float4(0.f, 0.f, 0.f, 0.f);
            float* o = out + (size_t)(b*POST_NMS + r)*5;
            o[0] = (float)b; o[1] = bx.x; o[2] = bx.y; o[3] = bx.z; o[4] = bx.w;
        }
    }
}

// ---------------------------------------------------------------------------
extern "C" void kernel_launch(void* const* d_in, const int* in_sizes, int n_in,
                              void* d_out, int out_size, void* d_ws, size_t ws_size,
                              hipStream_t stream) {
    (void)n_in; (void)out_size; (void)ws_size;
    const float* scores  = (const float*)d_in[0];
    const float* deltas  = (const float*)d_in[1];
    const float* im_info = (const float*)d_in[2];
    const float* anchors = (const float*)d_in[3];
    float* out = (float*)d_out;

    const int B = in_sizes[0] / (2*NA*HH*WW);   // = 2

    // ws layout: [hist B*4096 u32 | cnt 8 int | flags NBLK u32] (zeroed) |
    //            boxes4 | keys | ckeys | gboxes | mask
    size_t histB = (size_t)B * 4096 * sizeof(uint32_t);
    uint32_t* hist = (uint32_t*)d_ws;
    int* cnt = (int*)((char*)d_ws + histB);
    uint32_t* flags = (uint32_t*)((char*)d_ws + histB + 64);
    size_t zeroB = histB + 64 + NBLK * sizeof(uint32_t);
    float4* boxes4 = (float4*)((char*)d_ws + ((zeroB + 255) & ~(size_t)255));
    ull* keys  = (ull*)(boxes4 + (size_t)B*NPROP);
    ull* ckeys = keys + (size_t)B*NPROP;
    float4* gboxes = (float4*)(ckeys + (size_t)B*SELN);
    ull* mask = (ull*)(gboxes + (size_t)B*PRE_NMS);

    hipMemsetAsync(d_ws, 0, zeroB, stream);
    proposal_all<<<NBLK, NTHR, 0, stream>>>(scores, deltas, im_info, anchors,
                                            hist, cnt, flags,
                                            boxes4, keys, ckeys, gboxes, mask,
                                            out, B);
}

// Round 14
// 261.194 us; speedup vs baseline: 1.5983x; 1.5449x over previous
//
#include <hip/hip_runtime.h>
#include <stdint.h>

#define NA 9
#define HH 50
#define WW 50
#define NPROP (HH*WW*NA)      // 22500
#define PRE_NMS 4000
#define POST_NMS 300
#define NWORDS 63             // ceil(4000/64) suppression words per row
#define MROWS 4032            // padded rows per image (63 windows * 64)
#define SELN 8192             // compaction capacity (top-4000 + threshold-bucket slack)
#define NMS_T 0.7f
#define FSTRIDE 16.0f

typedef unsigned long long ull;

__device__ __forceinline__ uint32_t f32_ord(float s) {
    uint32_t u = __float_as_uint(s);
    return (u & 0x80000000u) ? ~u : (u | 0x80000000u);
}

// ---------------------------------------------------------------------------
// Kernel 1: decode boxes + build keys + histogram of top-16 key bits.
// ---------------------------------------------------------------------------
__global__ void decode_hist(const float* __restrict__ scores,
                            const float* __restrict__ deltas,
                            const float* __restrict__ im_info,
                            const float* __restrict__ anchors,
                            ull* __restrict__ keys,
                            float4* __restrict__ boxes4,
                            uint32_t* __restrict__ hist, int B) {
    int t = blockIdx.x * blockDim.x + threadIdx.x;
    if (t >= B * NPROP) return;
    int b = t / NPROP;
    int i = t % NPROP;

    int a   = i % NA;
    int pos = i / NA;          // h*W + w
    int w   = pos % WW;
    int h   = pos / WW;

    float score = scores[((size_t)b*2*NA + NA + a)*(HH*WW) + pos];
    ull key = ((ull)f32_ord(score) << 32) | (ull)(0xFFFFFFFFu - (uint32_t)i);
    keys[t] = key;
    atomicAdd(&hist[((uint32_t)b << 16) | (uint32_t)(key >> 48)], 1u);

    float ax1 = anchors[a*4+0], ay1 = anchors[a*4+1];
    float ax2 = anchors[a*4+2], ay2 = anchors[a*4+3];
    float sx = (float)w * FSTRIDE, sy = (float)h * FSTRIDE;
    float x1 = ax1 + sx, y1 = ay1 + sy, x2 = ax2 + sx, y2 = ay2 + sy;
    float bw = x2 - x1 + 1.0f;
    float bh = y2 - y1 + 1.0f;
    float cx = x1 + 0.5f * bw;
    float cy = y1 + 0.5f * bh;

    const float* dp = deltas + (size_t)b*4*NA*(HH*WW);
    float dx = dp[(4*a+0)*(HH*WW)+pos];
    float dy = dp[(4*a+1)*(HH*WW)+pos];
    float dw = dp[(4*a+2)*(HH*WW)+pos];
    float dh = dp[(4*a+3)*(HH*WW)+pos];

    float pcx = dx * bw + cx;
    float pcy = dy * bh + cy;
    float pw  = expf(dw) * bw;
    float ph  = expf(dh) * bh;

    float wmax = im_info[b*3+1] - 1.0f;
    float hmax = im_info[b*3+0] - 1.0f;
    float px1 = fminf(fmaxf(pcx - 0.5f*pw, 0.0f), wmax);
    float py1 = fminf(fmaxf(pcy - 0.5f*ph, 0.0f), hmax);
    float px2 = fminf(fmaxf(pcx + 0.5f*pw, 0.0f), wmax);
    float py2 = fminf(fmaxf(pcy + 0.5f*ph, 0.0f), hmax);

    boxes4[t] = make_float4(px1, py1, px2, py2);
}

// ---------------------------------------------------------------------------
// Kernel 2: one block per image. Find the 16-bit threshold bucket from the
// histogram, compact all keys in buckets >= threshold to global ckeys.
// ---------------------------------------------------------------------------
__global__ __launch_bounds__(1024) void compact_kernel(
        const ull* __restrict__ keys,
        const uint32_t* __restrict__ hist,
        ull* __restrict__ ckeys,
        int* __restrict__ mcount) {
    __shared__ int sA[1024], sB[1024]; // coarse sums + scan ping-pong
    __shared__ int nfine[64];
    __shared__ int sSeg, aboveC, thr, lcount;
    int img = blockIdx.x, tid = threadIdx.x;
    const uint32_t* h = hist + ((uint32_t)img << 16);

    // --- Phase A: coarse per-64-bucket sums (vectorized uint4 loads) ---
    {
        const uint4* h4 = (const uint4*)h;
        uint32_t s = 0;
        #pragma unroll
        for (int u = 0; u < 16; ++u) {
            uint4 v = h4[(tid << 4) | u];
            s += v.x + v.y + v.z + v.w;
        }
        sA[tid] = (int)s;
    }
    __syncthreads();
    // cumulative-from-top: cft[t] = sum_{u>=t} coarse[u]
    int* curp = sA; int* nxtp = sB;
    for (int d = 1; d < 1024; d <<= 1) {
        int v = curp[tid] + ((tid + d < 1024) ? curp[tid + d] : 0);
        nxtp[tid] = v;
        __syncthreads();
        int* tmp = curp; curp = nxtp; nxtp = tmp;
    }
    {
        int cftS  = curp[tid];
        int cftS1 = (tid < 1023) ? curp[tid + 1] : 0;
        if (cftS >= PRE_NMS && cftS1 < PRE_NMS) { sSeg = tid; aboveC = cftS1; }
    }
    __syncthreads();
    if (tid < 64) nfine[tid] = (int)h[(sSeg << 6) | tid];
    __syncthreads();
    if (tid == 0) {
        int cum = aboveC;          // count of keys in buckets > current
        int t = sSeg << 6;
        for (int w = 63; w >= 0; --w) {
            int nc = cum + nfine[w];
            if (nc >= PRE_NMS) { t = (sSeg << 6) | w; break; }
            cum = nc;
        }
        thr = t;
        lcount = 0;
    }
    __syncthreads();

    // --- Phase B: compact keys with bucket >= thr into global ckeys ---
    ull* ck = ckeys + (size_t)img * SELN;
    {
        const ull* kb = keys + (size_t)img * NPROP;
        int th = thr;
        for (int i = tid; i < NPROP; i += 1024) {
            ull key = kb[i];
            if ((int)(key >> 48) >= th) {
                int p = atomicAdd(&lcount, 1);
                if (p < SELN) ck[p] = key;
            }
        }
    }
    __syncthreads();
    int M = lcount; if (M > SELN) M = SELN;
    if (tid == 0) mcount[img] = M;
    for (int e = M + tid; e < SELN; e += 1024) ck[e] = 0ull;
}

// ---------------------------------------------------------------------------
// Kernel 3: rank-by-count scatter (keys unique => rank is exact permutation).
// ---------------------------------------------------------------------------
__global__ __launch_bounds__(256) void rank_scatter(
        const ull* __restrict__ ckeys,
        const int* __restrict__ mcount,
        const float4* __restrict__ boxes4,
        float4* __restrict__ gboxes) {
    __shared__ ull lk[SELN];
    __shared__ int sM;
    int img = blockIdx.y, rb = blockIdx.x, tid = threadIdx.x;
    if (tid == 0) sM = mcount[img];
    __syncthreads();
    int M = sM;
    if (rb * 256 >= M) return;
    int Ms = (M + 255) & ~255;

    const ull* kb = ckeys + (size_t)img * SELN;
    for (int e = tid; e < Ms; e += 256) lk[e] = (e < M) ? kb[e] : 0ull;
    __syncthreads();

    int row = rb * 256 + tid;
    if (row >= M) return;
    ull my = lk[row];

    int rank = 0;
    #pragma unroll 8
    for (int e = 0; e < Ms; ++e) rank += (lk[e] > my) ? 1 : 0;

    if (rank < PRE_NMS) {
        uint32_t idx = 0xFFFFFFFFu - (uint32_t)(my & 0xFFFFFFFFull);
        gboxes[(size_t)img*PRE_NMS + rank] = boxes4[(size_t)img*NPROP + idx];
    }
}

// ---------------------------------------------------------------------------
// Kernel 4: suppression bit-matrix. Off-diagonal (cb>rb): row-major words
// (bit k = row i suppresses col cb*64+k). DIAGONAL (cb==rb): TRANSPOSED —
// thread tid writes COLUMN tid's word (bit k = row k suppresses col tid).
// ---------------------------------------------------------------------------
__global__ __launch_bounds__(64) void mask_kernel(const float4* __restrict__ gboxes,
                                                  ull* __restrict__ mask) {
    int rb = blockIdx.x, cb = blockIdx.y, b = blockIdx.z;
    if (cb < rb) return;
    __shared__ float cx1[64], cy1[64], cx2[64], cy2[64], car[64];
    int tid = threadIdx.x;

    int j0 = cb*64 + tid;
    float4 cbx = (j0 < PRE_NMS) ? gboxes[(size_t)b*PRE_NMS + j0]
                                : make_float4(0.f,0.f,0.f,0.f);
    cx1[tid]=cbx.x; cy1[tid]=cbx.y; cx2[tid]=cbx.z; cy2[tid]=cbx.w;
    car[tid]=(cbx.z-cbx.x+1.0f)*(cbx.w-cbx.y+1.0f);
    __syncthreads();

    int i = rb*64 + tid;
    if (i >= PRE_NMS) return;
    float4 rbx = gboxes[(size_t)b*PRE_NMS + i];
    float ix1=rbx.x, iy1=rbx.y, ix2=rbx.z, iy2=rbx.w;
    float iarea=(ix2-ix1+1.0f)*(iy2-iy1+1.0f);

    const bool diag = (rb == cb);
    ull bits = 0;
    #pragma unroll 16
    for (int k = 0; k < 64; ++k) {
        float xx1 = fmaxf(ix1, cx1[k]);
        float yy1 = fmaxf(iy1, cy1[k]);
        float xx2 = fminf(ix2, cx2[k]);
        float yy2 = fminf(iy2, cy2[k]);
        float ww = fmaxf(xx2 - xx1 + 1.0f, 0.0f);
        float hh = fmaxf(yy2 - yy1 + 1.0f, 0.0f);
        float inter = ww * hh;
        float iou = inter / (iarea + car[k] - inter);
        // diag (transposed): bit k = row k suppresses col tid => tid > k
        // off-diag: bit k = row i suppresses col j=cb*64+k (j>i automatic)
        bool cond = diag ? (tid > k) : ((cb*64 + k) < PRE_NMS);
        if (cond & (iou > NMS_T)) bits |= (1ull << k);
    }
    mask[(((size_t)b*MROWS + i) << 6) + cb] = bits;
}

// ---------------------------------------------------------------------------
// Kernel 5: greedy scan, 256 threads. 4 waves cooperatively double-buffer the
// 32KB windows (8 x 16B loads/thread, issued BEFORE processing); wave 0 runs
// the ballot-based greedy loop (v4 logic, measured-correct). The 1-wave
// staging bandwidth pin (~1.2us/window) drops to ~0.4us with 4 waves.
// ---------------------------------------------------------------------------
__global__ __launch_bounds__(256) void scan_kernel(const ull* __restrict__ mask,
                                                   const float4* __restrict__ gboxes,
                                                   float* __restrict__ out) {
    __shared__ ull buf0[64*64];          // 32 KB window buffer A
    __shared__ ull buf1[64*64];          // 32 KB window buffer B
    __shared__ int keepIdx[POST_NMS];
    __shared__ int sKept, sDone;
    int b = blockIdx.x;
    int tid = threadIdx.x;
    int lane = tid & 63, wid = tid >> 6;
    const ull* mbase = mask + ((size_t)b * MROWS << 6);

    {   // stage window 0 with all 256 threads
        const ulonglong2* src = (const ulonglong2*)mbase;
        ulonglong2* dst = (ulonglong2*)buf0;
        #pragma unroll
        for (int k = 0; k < 8; ++k) dst[tid + k*256] = src[tid + k*256];
    }
    if (tid == 0) { sDone = 0; sKept = 0; }
    __syncthreads();

    ull supp = 0;
    if (lane == NWORDS-1) supp = 0xFFFFFFFF00000000ull;  // candidates >= 4000
    if (lane >= NWORDS)   supp = ~0ull;
    int kept = 0;
    int cur = 0;

    for (int wi = 0; wi < NWORDS; ++wi) {
        ulonglong2 pf[8];
        bool havepf = (wi + 1 < NWORDS);
        if (havepf) {   // all 4 waves issue next-window loads (overlap)
            const ulonglong2* src =
                (const ulonglong2*)(mbase + ((size_t)(wi + 1) << 12));
            #pragma unroll
            for (int k = 0; k < 8; ++k) pf[k] = src[tid + k*256];
        }
        if (wid == 0) {   // wave 0: process current window (v4 ballot logic)
            ull* bc = cur ? buf1 : buf0;
            ull tw = bc[lane * 64 + wi];          // transposed diag word
            ull avail = ~__shfl(supp, wi);
            ull keptmask = 0;
            bool done = false;
            while (avail) {
                int c = __builtin_ctzll(avail);
                if (lane == 0) keepIdx[kept] = (wi << 6) + c;
                ++kept;
                keptmask |= (1ull << c);
                if (kept >= POST_NMS) { done = true; break; }
                ull roww = __ballot((int)((tw >> c) & 1ull));
                avail &= ~roww;
                avail &= avail - 1;
            }
            if (!done) {   // future-window suppression for kept rows
                ull km = keptmask;
                while (km) {
                    int c = __builtin_ctzll(km); km &= km - 1;
                    ull r = (lane > wi && lane < NWORDS) ? bc[c * 64 + lane] : 0ull;
                    supp |= r;
                }
            }
            if (lane == 0) { sKept = kept; sDone = done ? 1 : 0; }
        }
        __syncthreads();
        if (sDone) break;
        if (havepf) {   // land the prefetch into the other buffer
            ulonglong2* dst = (ulonglong2*)(cur ? buf0 : buf1);
            #pragma unroll
            for (int k = 0; k < 8; ++k) dst[tid + k*256] = pf[k];
        }
        __syncthreads();
        cur ^= 1;
    }
    __syncthreads();

    int kfin = sKept;
    for (int r = tid; r < POST_NMS; r += 256) {
        float4 bx = (r < kfin) ? gboxes[(size_t)b*PRE_NMS + keepIdx[r]]
                               : make_float4(0.f, 0.f, 0.f, 0.f);
        float* o = out + (size_t)(b*POST_NMS + r)*5;
        o[0] = (float)b; o[1] = bx.x; o[2] = bx.y; o[3] = bx.z; o[4] = bx.w;
    }
}

// ---------------------------------------------------------------------------
extern "C" void kernel_launch(void* const* d_in, const int* in_sizes, int n_in,
                              void* d_out, int out_size, void* d_ws, size_t ws_size,
                              hipStream_t stream) {
    (void)n_in; (void)out_size; (void)ws_size;
    const float* scores  = (const float*)d_in[0];
    const float* deltas  = (const float*)d_in[1];
    const float* im_info = (const float*)d_in[2];
    const float* anchors = (const float*)d_in[3];
    float* out = (float*)d_out;

    const int B = in_sizes[0] / (2*NA*HH*WW);   // = 2

    // ws layout: boxes4 | gboxes | keys | ckeys | mask | hist | mcount
    float4* boxes4 = (float4*)d_ws;
    float4* gboxes = boxes4 + (size_t)B*NPROP;
    ull*    keys   = (ull*)(gboxes + (size_t)B*PRE_NMS);
    ull*    ckeys  = keys + (size_t)B*NPROP;
    ull*    mask   = ckeys + (size_t)B*SELN;
    uint32_t* hist = (uint32_t*)(mask + ((size_t)B*MROWS << 6));
    int*    mcount = (int*)(hist + (size_t)B*65536);

    hipMemsetAsync(hist, 0, (size_t)B*65536*sizeof(uint32_t), stream);
    decode_hist<<<(B*NPROP + 255)/256, 256, 0, stream>>>(scores, deltas, im_info,
                                                         anchors, keys, boxes4, hist, B);
    compact_kernel<<<B, 1024, 0, stream>>>(keys, hist, ckeys, mcount);
    dim3 rgrid(SELN/256, B);
    rank_scatter<<<rgrid, 256, 0, stream>>>(ckeys, mcount, boxes4, gboxes);
    dim3 mgrid(NWORDS, NWORDS, B);
    mask_kernel<<<mgrid, 64, 0, stream>>>(gboxes, mask);
    scan_kernel<<<B, 256, 0, stream>>>(mask, gboxes, out);
}